// Round 17
// baseline (72.478 us; speedup 1.0000x reference)
//
#include <hip/hip_runtime.h>
#include <stdint.h>

#define NN 16384
#define KK 64
#define DD 128
#define PP 8
#define NB 32
#define CH 64
#define CHD 32

typedef unsigned short ushort_t;
typedef __attribute__((ext_vector_type(8))) short short8;
typedef __attribute__((ext_vector_type(4))) float f32x4;

__device__ __forceinline__ ushort_t f2bf(float x) {
    unsigned u = __float_as_uint(x);
    u += 0x7fffu + ((u >> 16) & 1u);     // round-to-nearest-even
    return (ushort_t)(u >> 16);
}
__device__ __forceinline__ float silu_f(float v) { return v / (1.0f + __expf(-v)); }

// bf16 MFMA B-fragment straight from an f32 weight matrix (L2-hot)
__device__ __forceinline__ short8 ldWf(const float* __restrict__ W, int row, int col) {
    float4 a = *(const float4*)&W[(size_t)row * DD + col];
    float4 b = *(const float4*)&W[(size_t)row * DD + col + 4];
    short8 v;
    v[0] = (short)f2bf(a.x); v[1] = (short)f2bf(a.y);
    v[2] = (short)f2bf(a.z); v[3] = (short)f2bf(a.w);
    v[4] = (short)f2bf(b.x); v[5] = (short)f2bf(b.y);
    v[6] = (short)f2bf(b.z); v[7] = (short)f2bf(b.w);
    return v;
}

// ---------------- kB: [aux] + pre-MLP + LN + trig + blocked transposes ------
// main: 256 threads, 16-row tile, 1024 blocks (4/CU); W frags reg-prefetched.
__global__ __launch_bounds__(256, 4) void kB_pre(
        const float* __restrict__ x, const float* __restrict__ W1,
        const float* __restrict__ W2, const float* __restrict__ W3,
        const float* __restrict__ W4, const float* __restrict__ gamma,
        const float* __restrict__ beta, const float* __restrict__ kdr,
        const float* __restrict__ damp, const int* __restrict__ batch,
        ushort_t* __restrict__ Wb, int* __restrict__ starts_g,
        ushort_t* __restrict__ trig_rm, ushort_t* __restrict__ trigTb,
        ushort_t* __restrict__ xresTb) {
    __shared__ __align__(16) ushort_t xsb[16][136];   // x bf16, later trig tile
    __shared__ __align__(16) ushort_t t1b[16][136];   // t1, later LN(xres) bf16
    __shared__ float2 lnp[16][4];
    const int bid = blockIdx.x;

    if (bid < 8) {      // aux: W3/W4 -> Wb bf16 for kD
        int w = bid;
        const float* s = ((w >> 2) == 0 ? W3 : W4) + (w & 3) * 4096;
        ushort_t* d = Wb + (size_t)(w >> 2) * 16384 + (w & 3) * 4096;
        for (int i = threadIdx.x; i < 4096; i += 256) d[i] = f2bf(s[i]);
        return;
    }
    if (bid == 8) {     // aux: segment starts for kS/kD
        const int t = threadIdx.x;
        if (t <= NB) {
            int lo;
            if (t == NB) lo = NN;
            else {
                lo = 0; int hi = NN;
                while (lo < hi) { int mid = (lo + hi) >> 1; if (batch[mid] < t) lo = mid + 1; else hi = mid; }
            }
            starts_g[t] = lo;
        }
        return;
    }

    const int t = threadIdx.x, lane = t & 63, wv = t >> 6;   // wv 0..3
    const int ci = bid - 9;
    const int n0 = ci * 16;
    const int chf = wv * 32;              // column 32-slice per wave
    const int fr = (lane >> 4) * 8, cr = lane & 15, rr4 = (lane >> 4) * 4;

    // prefetch kdr/damp (hides under GEMMs)
    float2 kvp[2], dvp[2];
#pragma unroll
    for (int q = 0; q < 2; ++q) {
        int i = t + q * 256;
        int r = i >> 5, kk = (i & 31) * 2;
        kvp[q] = *(const float2*)&kdr[(size_t)(n0 + r) * KK + kk];
        dvp[q] = *(const float2*)&damp[(size_t)(n0 + r) * KK + kk];
    }
    // prefetch W1 GEMM1 fragments (hide L2 latency under x-stage + barrier)
    short8 w1f[2][4];
#pragma unroll
    for (int ks = 0; ks < 4; ++ks)
#pragma unroll
        for (int nt = 0; nt < 2; ++nt)
            w1f[nt][ks] = ldWf(W1, chf + nt * 16 + cr, ks * 32 + fr);
    {   // stage x -> bf16 (16 rows x 128 cols)
        const float4* src = (const float4*)(x + (size_t)n0 * DD);
        float4 v0 = src[t * 2], v1 = src[t * 2 + 1];
        int r = t >> 4, c = (t & 15) << 3;
        short8 pk;
        pk[0] = (short)f2bf(v0.x); pk[1] = (short)f2bf(v0.y);
        pk[2] = (short)f2bf(v0.z); pk[3] = (short)f2bf(v0.w);
        pk[4] = (short)f2bf(v1.x); pk[5] = (short)f2bf(v1.y);
        pk[6] = (short)f2bf(v1.z); pk[7] = (short)f2bf(v1.w);
        *(short8*)&xsb[r][c] = pk;
    }
    __syncthreads();

    f32x4 acc[2];
    const f32x4 z4 = {0.f, 0.f, 0.f, 0.f};

    // GEMM1 (W1 from regs)
#pragma unroll
    for (int nt = 0; nt < 2; ++nt) acc[nt] = z4;
#pragma unroll
    for (int ks = 0; ks < 4; ++ks) {
        short8 af = *(const short8*)&xsb[cr][ks * 32 + fr];
#pragma unroll
        for (int nt = 0; nt < 2; ++nt)
            acc[nt] = __builtin_amdgcn_mfma_f32_16x16x32_bf16(af, w1f[nt][ks], acc[nt], 0, 0, 0);
    }
#pragma unroll
    for (int nt = 0; nt < 2; ++nt)
#pragma unroll
        for (int r = 0; r < 4; ++r)
            t1b[rr4 + r][chf + nt * 16 + cr] = f2bf(silu_f(acc[nt][r]));

    // prefetch W2 fragments + residual x (hide under the t1 barrier)
    short8 w2f[2][4];
#pragma unroll
    for (int ks = 0; ks < 4; ++ks)
#pragma unroll
        for (int nt = 0; nt < 2; ++nt)
            w2f[nt][ks] = ldWf(W2, chf + nt * 16 + cr, ks * 32 + fr);
    float xr[2][4];
#pragma unroll
    for (int nt = 0; nt < 2; ++nt)
#pragma unroll
        for (int r = 0; r < 4; ++r)
            xr[nt][r] = x[(size_t)(n0 + rr4 + r) * DD + chf + nt * 16 + cr];
    __syncthreads();

    // GEMM2 (W2 from regs) + trig + residual + LN partials
#pragma unroll
    for (int nt = 0; nt < 2; ++nt) acc[nt] = z4;
#pragma unroll
    for (int ks = 0; ks < 4; ++ks) {
        short8 af = *(const short8*)&t1b[cr][ks * 32 + fr];
#pragma unroll
        for (int nt = 0; nt < 2; ++nt)
            acc[nt] = __builtin_amdgcn_mfma_f32_16x16x32_bf16(af, w2f[nt][ks], acc[nt], 0, 0, 0);
    }
#pragma unroll
    for (int q = 0; q < 2; ++q) {
        int i = t + q * 256;
        int r = i >> 5, kk = (i & 31) * 2;
        float s0, c0, s1, c1;
        __sincosf(kvp[q].x, &s0, &c0);
        __sincosf(kvp[q].y, &s1, &c1);
        ushort_t rc0 = f2bf(c0 * dvp[q].x), rc1 = f2bf(c1 * dvp[q].y);
        ushort_t is0 = f2bf(s0 * dvp[q].x), is1 = f2bf(s1 * dvp[q].y);
        xsb[r][kk] = rc0; xsb[r][kk + 1] = rc1;
        xsb[r][64 + kk] = is0; xsb[r][64 + kk + 1] = is1;
        ushort2 a; a.x = rc0; a.y = rc1;
        ushort2 b; b.x = is0; b.y = is1;
        *(ushort2*)&trig_rm[(size_t)(n0 + r) * 128 + kk] = a;
        *(ushort2*)&trig_rm[(size_t)(n0 + r) * 128 + 64 + kk] = b;
    }
    float g[2], be[2];
#pragma unroll
    for (int nt = 0; nt < 2; ++nt) {
        g[nt] = gamma[chf + nt * 16 + cr];
        be[nt] = beta[chf + nt * 16 + cr];
    }
#pragma unroll
    for (int r = 0; r < 4; ++r) {
        float s = 0.f, sq = 0.f;
#pragma unroll
        for (int nt = 0; nt < 2; ++nt) {
            float v = xr[nt][r] + silu_f(acc[nt][r]);
            acc[nt][r] = v;
            s += v; sq += v * v;
        }
#pragma unroll
        for (int off = 1; off < 16; off <<= 1) {
            s += __shfl_xor(s, off);
            sq += __shfl_xor(sq, off);
        }
        if (cr == 0) {
            float2 p; p.x = s; p.y = sq;
            lnp[rr4 + r][wv] = p;
        }
    }
    __syncthreads();

    // LN finalize -> t1b
#pragma unroll
    for (int r = 0; r < 4; ++r) {
        int row = rr4 + r;
        float2 a0 = lnp[row][0], a1 = lnp[row][1], a2 = lnp[row][2], a3 = lnp[row][3];
        float s = a0.x + a1.x + a2.x + a3.x, sq = a0.y + a1.y + a2.y + a3.y;
        float mu = s * (1.0f / 128.0f);
        float var = sq * (1.0f / 128.0f) - mu * mu;
        float rs = rsqrtf(var + 1e-5f);
#pragma unroll
        for (int nt = 0; nt < 2; ++nt)
            t1b[row][chf + nt * 16 + cr] = f2bf((acc[nt][r] - mu) * rs * g[nt] + be[nt]);
    }
    __syncthreads();

    // blocked transposed writes (this 16-row quarter of a 64-row chunk)
    {
        int m = t >> 1, hh = (t & 1) * 8;
        size_t base = (size_t)(ci >> 2) * 8192 + (size_t)m * 64 + (ci & 3) * 16 + hh;
        short8 v;
#pragma unroll
        for (int j = 0; j < 8; ++j) v[j] = (short)xsb[hh + j][m];
        *(short8*)&trigTb[base] = v;
#pragma unroll
        for (int j = 0; j < 8; ++j) v[j] = (short)t1b[hh + j][m];
        *(short8*)&xresTb[base] = v;
    }
}

// ---------------- kS: direct-global fragments, no LDS, no barriers ----------
// block (b=bid&31, g2): fragments stream straight from the L2-hot blocked
// buffers (contiguous 16KB/chunk, XCD-shared); pure load->MFMA chain.
__global__ __launch_bounds__(256, 4) void kS_scatter(
        const int* __restrict__ starts_g,
        const ushort_t* __restrict__ xresTb, const ushort_t* __restrict__ trigTb,
        const float* __restrict__ dp, const float* __restrict__ wup,
        ushort_t* __restrict__ SFTb) {
    const int b = blockIdx.x & 31, g2 = blockIdx.x >> 5;     // g2 0..15
    const int d0 = (g2 & 7) * 16, mh = (g2 >> 3) * 64;
    const int t = threadIdx.x, lane = t & 63, wv = t >> 6;   // wv 0..3
    const int segs = starts_g[b], sege = starts_g[b + 1];

    const int fr = (lane >> 4) * 8, cr = lane & 15, rr4 = (lane >> 4) * 4;
    const f32x4 z4 = {0.f, 0.f, 0.f, 0.f};
    f32x4 acc = z4;

    const size_t xoff = (size_t)(d0 + cr) * 64;
    const size_t toff = (size_t)(mh + wv * 16 + cr) * 64;

    for (int r0 = segs & ~(CH - 1); r0 < sege; r0 += CH) {
        int lo = segs - r0; if (lo < 0) lo = 0;
        int hi = sege - r0; if (hi > CH) hi = CH;
        const size_t cb = (size_t)(r0 >> 6) * 8192;
        const ushort_t* xp = xresTb + cb + xoff;
        const ushort_t* tp = trigTb + cb + toff;
        if (lo == 0 && hi == CH) {
#pragma unroll
            for (int ks = 0; ks < 2; ++ks) {
                short8 af = *(const short8*)(xp + ks * 32 + fr);
                short8 bf = *(const short8*)(tp + ks * 32 + fr);
                acc = __builtin_amdgcn_mfma_f32_16x16x32_bf16(af, bf, acc, 0, 0, 0);
            }
        } else {
#pragma unroll
            for (int ks = 0; ks < 2; ++ks) {
                short8 af, bf;
#pragma unroll
                for (int e = 0; e < 8; ++e) {
                    int c = ks * 32 + fr + e;
                    bool ok = (c >= lo) && (c < hi);
                    af[e] = ok ? (short)xp[c] : (short)0;
                    bf[e] = ok ? (short)tp[c] : (short)0;
                }
                acc = __builtin_amdgcn_mfma_f32_16x16x32_bf16(af, bf, acc, 0, 0, 0);
            }
        }
    }

    // kfilter + bf16 store
    const int m = mh + wv * 16 + cr;
    const int k = m & 63;
    float4 p0 = *(const float4*)&dp[k * PP];
    float4 p1 = *(const float4*)&dp[k * PP + 4];
#pragma unroll
    for (int r = 0; r < 4; ++r) {
        int d = d0 + rr4 + r;
        float4 w0 = *(const float4*)&wup[d * PP];
        float4 w1 = *(const float4*)&wup[d * PP + 4];
        float kf = p0.x * w0.x + p0.y * w0.y + p0.z * w0.z + p0.w * w0.w
                 + p1.x * w1.x + p1.y * w1.y + p1.z * w1.z + p1.w * w1.w;
        SFTb[((size_t)b * 128 + d) * 128 + m] = f2bf(acc[r] * kf);
    }
}

// ---------------- kD: gather (direct-global SFT frags) + post-MLP -> out ----
__global__ __launch_bounds__(256, 4) void kD_post(
        const float* __restrict__ x, const int* __restrict__ starts_g,
        const ushort_t* __restrict__ trig_rm, const ushort_t* __restrict__ SFTb,
        const ushort_t* __restrict__ Wb, float* __restrict__ out) {
    __shared__ __align__(16) ushort_t xs[32][136];
    __shared__ __align__(16) ushort_t t1[32][136];
    __shared__ int starts[NB + 1];
    __shared__ int offs[NB + 1];
    const int t = threadIdx.x, lane = t & 63, wv = t >> 6;   // wv 0..3
    const int fr = (lane >> 4) * 8, cr = lane & 15, rr4 = (lane >> 4) * 4;
    const f32x4 z4 = {0.f, 0.f, 0.f, 0.f};

    if (t < 33) starts[t] = starts_g[t];
    __syncthreads();
    if (t == 0) {
        int off = 0;
        for (int b = 0; b < NB; ++b) {
            offs[b] = off;
            off += (starts[b + 1] - starts[b] + CHD - 1) / CHD;
        }
        offs[NB] = off;
    }
    __syncthreads();
    const int nwl = offs[NB];
    const int c = (blockIdx.x & 7) * 72 + (blockIdx.x >> 3);   // XCD-local segments
    if (c >= nwl) return;
    int b = 0;
    while (offs[b + 1] <= c) ++b;
    const int r0c = starts[b] + (c - offs[b]) * CHD;
    const int len = min(CHD, starts[b + 1] - r0c);

    const int ar0 = (wv & 1) * 16;
    const int chf = (wv >> 1) * 64;
    const ushort_t* W3b = Wb;
    const ushort_t* W4b = Wb + 16384;
    const ushort_t* SFT = SFTb + (size_t)b * 16384;

    // prefetch gather A-fragments + x residual (issue early, overlap)
    int nrow = r0c + ar0 + cr; if (nrow >= NN) nrow = NN - 1;
    short8 afp[4];
#pragma unroll
    for (int ks = 0; ks < 4; ++ks)
        afp[ks] = *(const short8*)&trig_rm[(size_t)nrow * 128 + ks * 32 + fr];
    float xr[4][4];
#pragma unroll
    for (int nt = 0; nt < 4; ++nt)
#pragma unroll
        for (int r = 0; r < 4; ++r) {
            int row = r0c + ar0 + rr4 + r; if (row >= NN) row = NN - 1;
            xr[nt][r] = x[(size_t)row * DD + chf + nt * 16 + cr];
        }

    // gather: B-frags straight from L2/L3-hot SFTb
    f32x4 g4[4];
#pragma unroll
    for (int nt = 0; nt < 4; ++nt) g4[nt] = z4;
#pragma unroll
    for (int ks = 0; ks < 4; ++ks) {
#pragma unroll
        for (int nt = 0; nt < 4; ++nt) {
            short8 bf = *(const short8*)&SFT[(size_t)(chf + nt * 16 + cr) * 128 + ks * 32 + fr];
            g4[nt] = __builtin_amdgcn_mfma_f32_16x16x32_bf16(afp[ks], bf, g4[nt], 0, 0, 0);
        }
    }

    // xg = x + msg
    float xk[4][4];
#pragma unroll
    for (int nt = 0; nt < 4; ++nt)
#pragma unroll
        for (int r = 0; r < 4; ++r) {
            int rr = ar0 + rr4 + r;
            float xv = xr[nt][r] + g4[nt][r];
            xk[nt][r] = xv;
            xs[rr][chf + nt * 16 + cr] = f2bf(xv);
        }
    __syncthreads();

    // GEMM1 (W3) -> t1
#pragma unroll
    for (int nt = 0; nt < 4; ++nt) g4[nt] = z4;
#pragma unroll
    for (int ks = 0; ks < 4; ++ks) {
        short8 af = *(const short8*)&xs[ar0 + cr][ks * 32 + fr];
#pragma unroll
        for (int nt = 0; nt < 4; ++nt) {
            short8 bf = *(const short8*)&W3b[(size_t)(chf + nt * 16 + cr) * DD + ks * 32 + fr];
            g4[nt] = __builtin_amdgcn_mfma_f32_16x16x32_bf16(af, bf, g4[nt], 0, 0, 0);
        }
    }
#pragma unroll
    for (int nt = 0; nt < 4; ++nt)
#pragma unroll
        for (int r = 0; r < 4; ++r)
            t1[ar0 + rr4 + r][chf + nt * 16 + cr] = f2bf(silu_f(g4[nt][r]));
    __syncthreads();

    // GEMM2 (W4) + residual -> out (masked)
#pragma unroll
    for (int nt = 0; nt < 4; ++nt) g4[nt] = z4;
#pragma unroll
    for (int ks = 0; ks < 4; ++ks) {
        short8 af = *(const short8*)&t1[ar0 + cr][ks * 32 + fr];
#pragma unroll
        for (int nt = 0; nt < 4; ++nt) {
            short8 bf = *(const short8*)&W4b[(size_t)(chf + nt * 16 + cr) * DD + ks * 32 + fr];
            g4[nt] = __builtin_amdgcn_mfma_f32_16x16x32_bf16(af, bf, g4[nt], 0, 0, 0);
        }
    }
#pragma unroll
    for (int nt = 0; nt < 4; ++nt)
#pragma unroll
        for (int r = 0; r < 4; ++r) {
            int rr = ar0 + rr4 + r;
            if (rr < len)
                out[(size_t)(r0c + rr) * DD + chf + nt * 16 + cr] = xk[nt][r] + silu_f(g4[nt][r]);
        }
}

extern "C" void kernel_launch(void* const* d_in, const int* in_sizes, int n_in,
                              void* d_out, int out_size, void* d_ws, size_t ws_size,
                              hipStream_t stream) {
    const float* x      = (const float*)d_in[0];
    const float* kdr    = (const float*)d_in[1];
    const float* damp   = (const float*)d_in[2];
    const int*   batch  = (const int*)d_in[3];
    const float* dp     = (const float*)d_in[4];
    const float* W_pre1 = (const float*)d_in[5];
    const float* W_pre2 = (const float*)d_in[6];
    const float* gamma  = (const float*)d_in[7];
    const float* beta   = (const float*)d_in[8];
    const float* W_up   = (const float*)d_in[9];
    const float* W_upd1 = (const float*)d_in[10];
    const float* W_upd2 = (const float*)d_in[11];
    float* out = (float*)d_out;

    char* w = (char*)d_ws;
    ushort_t* Wb       = (ushort_t*)w;                     // 64 KiB used (W3b|W4b)
    int*      starts_g = (int*)(w + 65536);                // 33 ints
    size_t o = 131072;
    ushort_t* trig_rm = (ushort_t*)(w + o);  o += (size_t)NN * 128 * 2;       // 4 MB
    ushort_t* trigTb  = (ushort_t*)(w + o);  o += (size_t)NN * 128 * 2;       // 4 MB
    ushort_t* xresTb  = (ushort_t*)(w + o);  o += (size_t)NN * 128 * 2;       // 4 MB
    ushort_t* SFTb    = (ushort_t*)(w + o);  o += (size_t)NB * 128 * 128 * 2; // 1 MB

    hipLaunchKernelGGL(kB_pre, dim3(9 + NN / 16), dim3(256), 0, stream,
                       x, W_pre1, W_pre2, W_upd1, W_upd2, gamma, beta,
                       kdr, damp, batch, Wb, starts_g, trig_rm, trigTb, xresTb);
    hipLaunchKernelGGL(kS_scatter, dim3(NB * 16), dim3(256), 0, stream,
                       starts_g, xresTb, trigTb, dp, W_up, SFTb);
    hipLaunchKernelGGL(kD_post, dim3(576), dim3(256), 0, stream,
                       x, starts_g, trig_rm, SFTb, Wb, out);
}

// Round 18
// 64.123 us; speedup vs baseline: 1.1303x; 1.1303x over previous
//
#include <hip/hip_runtime.h>
#include <stdint.h>

#define NN 16384
#define KK 64
#define DD 128
#define PP 8
#define NB 32
#define CH 64
#define CHD 32

typedef unsigned short ushort_t;
typedef __attribute__((ext_vector_type(8))) short short8;
typedef __attribute__((ext_vector_type(4))) float f32x4;

__device__ __forceinline__ ushort_t f2bf(float x) {
    unsigned u = __float_as_uint(x);
    u += 0x7fffu + ((u >> 16) & 1u);     // round-to-nearest-even
    return (ushort_t)(u >> 16);
}
__device__ __forceinline__ float silu_f(float v) { return v / (1.0f + __expf(-v)); }

// bf16 MFMA B-fragment straight from an f32 weight matrix (L2-hot)
__device__ __forceinline__ short8 ldWf(const float* __restrict__ W, int row, int col) {
    float4 a = *(const float4*)&W[(size_t)row * DD + col];
    float4 b = *(const float4*)&W[(size_t)row * DD + col + 4];
    short8 v;
    v[0] = (short)f2bf(a.x); v[1] = (short)f2bf(a.y);
    v[2] = (short)f2bf(a.z); v[3] = (short)f2bf(a.w);
    v[4] = (short)f2bf(b.x); v[5] = (short)f2bf(b.y);
    v[6] = (short)f2bf(b.z); v[7] = (short)f2bf(b.w);
    return v;
}

// ---------------- kB: [aux] + pre-MLP + LN + trig + blocked transposes ------
// main: 256 threads, 16-row tile, 1024 blocks (4/CU).
__global__ __launch_bounds__(256, 4) void kB_pre(
        const float* __restrict__ x, const float* __restrict__ W1,
        const float* __restrict__ W2, const float* __restrict__ W3,
        const float* __restrict__ W4, const float* __restrict__ gamma,
        const float* __restrict__ beta, const float* __restrict__ kdr,
        const float* __restrict__ damp, const int* __restrict__ batch,
        ushort_t* __restrict__ Wb, int* __restrict__ starts_g,
        ushort_t* __restrict__ trig_rm, ushort_t* __restrict__ trigTb,
        ushort_t* __restrict__ xresTb) {
    __shared__ __align__(16) ushort_t xsb[16][136];   // x bf16, later trig tile
    __shared__ __align__(16) ushort_t t1b[16][136];   // t1, later LN(xres) bf16
    __shared__ float2 lnp[16][4];
    const int bid = blockIdx.x;

    if (bid < 8) {      // aux: W3/W4 -> Wb bf16 for kD
        int w = bid;
        const float* s = ((w >> 2) == 0 ? W3 : W4) + (w & 3) * 4096;
        ushort_t* d = Wb + (size_t)(w >> 2) * 16384 + (w & 3) * 4096;
        for (int i = threadIdx.x; i < 4096; i += 256) d[i] = f2bf(s[i]);
        return;
    }
    if (bid == 8) {     // aux: segment starts for kS/kD
        const int t = threadIdx.x;
        if (t <= NB) {
            int lo;
            if (t == NB) lo = NN;
            else {
                lo = 0; int hi = NN;
                while (lo < hi) { int mid = (lo + hi) >> 1; if (batch[mid] < t) lo = mid + 1; else hi = mid; }
            }
            starts_g[t] = lo;
        }
        return;
    }

    const int t = threadIdx.x, lane = t & 63, wv = t >> 6;   // wv 0..3
    const int ci = bid - 9;
    const int n0 = ci * 16;
    const int chf = wv * 32;              // column 32-slice per wave
    const int fr = (lane >> 4) * 8, cr = lane & 15, rr4 = (lane >> 4) * 4;

    // prefetch kdr/damp (hides under GEMMs)
    float2 kvp[2], dvp[2];
#pragma unroll
    for (int q = 0; q < 2; ++q) {
        int i = t + q * 256;
        int r = i >> 5, kk = (i & 31) * 2;
        kvp[q] = *(const float2*)&kdr[(size_t)(n0 + r) * KK + kk];
        dvp[q] = *(const float2*)&damp[(size_t)(n0 + r) * KK + kk];
    }
    {   // stage x -> bf16 (16 rows x 128 cols)
        const float4* src = (const float4*)(x + (size_t)n0 * DD);
        float4 v0 = src[t * 2], v1 = src[t * 2 + 1];
        int r = t >> 4, c = (t & 15) << 3;
        short8 pk;
        pk[0] = (short)f2bf(v0.x); pk[1] = (short)f2bf(v0.y);
        pk[2] = (short)f2bf(v0.z); pk[3] = (short)f2bf(v0.w);
        pk[4] = (short)f2bf(v1.x); pk[5] = (short)f2bf(v1.y);
        pk[6] = (short)f2bf(v1.z); pk[7] = (short)f2bf(v1.w);
        *(short8*)&xsb[r][c] = pk;
    }
    __syncthreads();

    f32x4 acc[2];
    const f32x4 z4 = {0.f, 0.f, 0.f, 0.f};

    // GEMM1 (W1 on-the-fly bf16)
#pragma unroll
    for (int nt = 0; nt < 2; ++nt) acc[nt] = z4;
#pragma unroll
    for (int ks = 0; ks < 4; ++ks) {
        short8 af = *(const short8*)&xsb[cr][ks * 32 + fr];
#pragma unroll
        for (int nt = 0; nt < 2; ++nt) {
            short8 bf = ldWf(W1, chf + nt * 16 + cr, ks * 32 + fr);
            acc[nt] = __builtin_amdgcn_mfma_f32_16x16x32_bf16(af, bf, acc[nt], 0, 0, 0);
        }
    }
#pragma unroll
    for (int nt = 0; nt < 2; ++nt)
#pragma unroll
        for (int r = 0; r < 4; ++r)
            t1b[rr4 + r][chf + nt * 16 + cr] = f2bf(silu_f(acc[nt][r]));
    __syncthreads();

    // GEMM2 (W2 on-the-fly) + trig + residual + LN partials
#pragma unroll
    for (int nt = 0; nt < 2; ++nt) acc[nt] = z4;
#pragma unroll
    for (int ks = 0; ks < 4; ++ks) {
        short8 af = *(const short8*)&t1b[cr][ks * 32 + fr];
#pragma unroll
        for (int nt = 0; nt < 2; ++nt) {
            short8 bf = ldWf(W2, chf + nt * 16 + cr, ks * 32 + fr);
            acc[nt] = __builtin_amdgcn_mfma_f32_16x16x32_bf16(af, bf, acc[nt], 0, 0, 0);
        }
    }
#pragma unroll
    for (int q = 0; q < 2; ++q) {
        int i = t + q * 256;
        int r = i >> 5, kk = (i & 31) * 2;
        float s0, c0, s1, c1;
        __sincosf(kvp[q].x, &s0, &c0);
        __sincosf(kvp[q].y, &s1, &c1);
        ushort_t rc0 = f2bf(c0 * dvp[q].x), rc1 = f2bf(c1 * dvp[q].y);
        ushort_t is0 = f2bf(s0 * dvp[q].x), is1 = f2bf(s1 * dvp[q].y);
        xsb[r][kk] = rc0; xsb[r][kk + 1] = rc1;
        xsb[r][64 + kk] = is0; xsb[r][64 + kk + 1] = is1;
        ushort2 a; a.x = rc0; a.y = rc1;
        ushort2 b; b.x = is0; b.y = is1;
        *(ushort2*)&trig_rm[(size_t)(n0 + r) * 128 + kk] = a;
        *(ushort2*)&trig_rm[(size_t)(n0 + r) * 128 + 64 + kk] = b;
    }
    float g[2], be[2];
#pragma unroll
    for (int nt = 0; nt < 2; ++nt) {
        g[nt] = gamma[chf + nt * 16 + cr];
        be[nt] = beta[chf + nt * 16 + cr];
    }
#pragma unroll
    for (int r = 0; r < 4; ++r) {
        int row = n0 + rr4 + r;
        float s = 0.f, sq = 0.f;
#pragma unroll
        for (int nt = 0; nt < 2; ++nt) {
            float v = x[(size_t)row * DD + chf + nt * 16 + cr] + silu_f(acc[nt][r]);
            acc[nt][r] = v;
            s += v; sq += v * v;
        }
#pragma unroll
        for (int off = 1; off < 16; off <<= 1) {
            s += __shfl_xor(s, off);
            sq += __shfl_xor(sq, off);
        }
        if (cr == 0) {
            float2 p; p.x = s; p.y = sq;
            lnp[rr4 + r][wv] = p;
        }
    }
    __syncthreads();

    // LN finalize -> t1b
#pragma unroll
    for (int r = 0; r < 4; ++r) {
        int row = rr4 + r;
        float2 a0 = lnp[row][0], a1 = lnp[row][1], a2 = lnp[row][2], a3 = lnp[row][3];
        float s = a0.x + a1.x + a2.x + a3.x, sq = a0.y + a1.y + a2.y + a3.y;
        float mu = s * (1.0f / 128.0f);
        float var = sq * (1.0f / 128.0f) - mu * mu;
        float rs = rsqrtf(var + 1e-5f);
#pragma unroll
        for (int nt = 0; nt < 2; ++nt)
            t1b[row][chf + nt * 16 + cr] = f2bf((acc[nt][r] - mu) * rs * g[nt] + be[nt]);
    }
    __syncthreads();

    // blocked transposed writes (this 16-row quarter of a 64-row chunk)
    {
        int m = t >> 1, hh = (t & 1) * 8;
        size_t base = (size_t)(ci >> 2) * 8192 + (size_t)m * 64 + (ci & 3) * 16 + hh;
        short8 v;
#pragma unroll
        for (int j = 0; j < 8; ++j) v[j] = (short)xsb[hh + j][m];
        *(short8*)&trigTb[base] = v;
#pragma unroll
        for (int j = 0; j < 8; ++j) v[j] = (short)t1b[hh + j][m];
        *(short8*)&xresTb[base] = v;
    }
}

// ---------------- kS: per-(segment, d-group, m-quarter) scatter -> SFTb -----
// 1024 blocks x 128 threads (8 blocks/CU), ~7KB LDS, XCD-local (bid%8=b%8).
__global__ __launch_bounds__(128, 8) void kS_scatter(
        const int* __restrict__ starts_g,
        const ushort_t* __restrict__ xresTb, const ushort_t* __restrict__ trigTb,
        const float* __restrict__ dp, const float* __restrict__ wup,
        ushort_t* __restrict__ SFTb) {
    __shared__ __align__(16) ushort_t xt[16][72];
    __shared__ __align__(16) ushort_t tt[32][72];
    __shared__ int seg2[2];
    const int b = blockIdx.x & 31, g2 = blockIdx.x >> 5;     // g2 0..31
    const int d0 = (g2 & 7) * 16, mh = (g2 >> 3) * 32;
    const int t = threadIdx.x, lane = t & 63, wv = t >> 6;   // wv 0..1

    if (t < 2) seg2[t] = starts_g[b + t];
    __syncthreads();
    const int segs = seg2[0], sege = seg2[1];

    const int fr = (lane >> 4) * 8, cr = lane & 15, rr4 = (lane >> 4) * 4;
    const f32x4 z4 = {0.f, 0.f, 0.f, 0.f};
    f32x4 acc = z4;

    for (int r0 = segs & ~(CH - 1); r0 < sege; r0 += CH) {
        int lo = segs - r0; if (lo < 0) lo = 0;
        int hi = sege - r0; if (hi > CH) hi = CH;
        const size_t cb = (size_t)(r0 >> 6) * 8192;
        for (int i = t; i < 96; i += 128) {
            int row = i >> 1, h = (i & 1) * 32;
            const ushort_t* src = (row < 16 ? xresTb + cb + (size_t)(d0 + row) * 64
                                            : trigTb + cb + (size_t)(mh + row - 16) * 64) + h;
            ushort_t* dst = (row < 16 ? &xt[row][h] : &tt[row - 16][h]);
            if (lo == 0 && hi == CH) {
#pragma unroll
                for (int q = 0; q < 4; ++q) *(short8*)(dst + q * 8) = *(const short8*)(src + q * 8);
            } else {
                for (int j = 0; j < 32; ++j) { int c = h + j; dst[j] = (c >= lo && c < hi) ? src[j] : (ushort_t)0; }
            }
        }
        __syncthreads();
#pragma unroll
        for (int ks = 0; ks < 2; ++ks) {
            short8 af = *(const short8*)&xt[cr][ks * 32 + fr];
            short8 bf = *(const short8*)&tt[wv * 16 + cr][ks * 32 + fr];
            acc = __builtin_amdgcn_mfma_f32_16x16x32_bf16(af, bf, acc, 0, 0, 0);
        }
        __syncthreads();
    }

    // kfilter + bf16 store
    const int m = mh + wv * 16 + cr;
    const int k = m & 63;
    float4 p0 = *(const float4*)&dp[k * PP];
    float4 p1 = *(const float4*)&dp[k * PP + 4];
#pragma unroll
    for (int r = 0; r < 4; ++r) {
        int d = d0 + rr4 + r;
        float4 w0 = *(const float4*)&wup[d * PP];
        float4 w1 = *(const float4*)&wup[d * PP + 4];
        float kf = p0.x * w0.x + p0.y * w0.y + p0.z * w0.z + p0.w * w0.w
                 + p1.x * w1.x + p1.y * w1.y + p1.z * w1.z + p1.w * w1.w;
        SFTb[((size_t)b * 128 + d) * 128 + m] = f2bf(acc[r] * kf);
    }
}

// ---------------- kD: gather + post-MLP + residual -> out (32-row chunks) ---
__global__ __launch_bounds__(256, 3) void kD_post(
        const float* __restrict__ x, const int* __restrict__ starts_g,
        const ushort_t* __restrict__ trig_rm, const ushort_t* __restrict__ SFTb,
        const ushort_t* __restrict__ Wb, float* __restrict__ out) {
    __shared__ __align__(16) ushort_t sft[128 * 136];   // t1 aliases after gather
    __shared__ __align__(16) ushort_t xs[32][136];
    __shared__ int starts[NB + 1];
    __shared__ int offs[NB + 1];
    const int t = threadIdx.x, lane = t & 63, wv = t >> 6;   // wv 0..3
    const int fr = (lane >> 4) * 8, cr = lane & 15, rr4 = (lane >> 4) * 4;
    const f32x4 z4 = {0.f, 0.f, 0.f, 0.f};

    if (t < 33) starts[t] = starts_g[t];
    __syncthreads();
    if (t == 0) {
        int off = 0;
        for (int b = 0; b < NB; ++b) {
            offs[b] = off;
            off += (starts[b + 1] - starts[b] + CHD - 1) / CHD;
        }
        offs[NB] = off;
    }
    __syncthreads();
    const int nwl = offs[NB];
    const int c = (blockIdx.x & 7) * 72 + (blockIdx.x >> 3);   // XCD-local segments
    if (c >= nwl) return;
    int b = 0;
    while (offs[b + 1] <= c) ++b;
    const int r0c = starts[b] + (c - offs[b]) * CHD;
    const int len = min(CHD, starts[b + 1] - r0c);

    const int ar0 = (wv & 1) * 16;
    const int chf = (wv >> 1) * 64;
    const ushort_t* W3b = Wb;
    const ushort_t* W4b = Wb + 16384;

    // prefetch gather A-fragments + x residual (hide under sft stage)
    int nrow = r0c + ar0 + cr; if (nrow >= NN) nrow = NN - 1;
    short8 afp[4];
#pragma unroll
    for (int ks = 0; ks < 4; ++ks)
        afp[ks] = *(const short8*)&trig_rm[(size_t)nrow * 128 + ks * 32 + fr];
    float xr[4][4];
#pragma unroll
    for (int nt = 0; nt < 4; ++nt)
#pragma unroll
        for (int r = 0; r < 4; ++r) {
            int row = r0c + ar0 + rr4 + r; if (row >= NN) row = NN - 1;
            xr[nt][r] = x[(size_t)row * DD + chf + nt * 16 + cr];
        }

    // stage SFTb[b] (32KB contiguous)
    {
        const ushort_t* srcS = SFTb + (size_t)b * 16384;
        for (int i = t; i < 2048; i += 256) {
            int r = i >> 4, cc = (i & 15) * 8;
            *(short8*)&sft[r * 136 + cc] = *(const short8*)(srcS + r * 128 + cc);
        }
    }
    __syncthreads();

    // gather
    f32x4 g4[4];
#pragma unroll
    for (int nt = 0; nt < 4; ++nt) g4[nt] = z4;
#pragma unroll
    for (int ks = 0; ks < 4; ++ks) {
#pragma unroll
        for (int nt = 0; nt < 4; ++nt) {
            short8 bf = *(const short8*)&sft[(chf + nt * 16 + cr) * 136 + ks * 32 + fr];
            g4[nt] = __builtin_amdgcn_mfma_f32_16x16x32_bf16(afp[ks], bf, g4[nt], 0, 0, 0);
        }
    }

    // xg = x + msg
    float xk[4][4];
#pragma unroll
    for (int nt = 0; nt < 4; ++nt)
#pragma unroll
        for (int r = 0; r < 4; ++r) {
            int rr = ar0 + rr4 + r;
            float xv = xr[nt][r] + g4[nt][r];
            xk[nt][r] = xv;
            xs[rr][chf + nt * 16 + cr] = f2bf(xv);
        }
    __syncthreads();   // sft gather reads done -> t1 alias safe; xs ready

    // GEMM1 (W3) -> t1 (aliases sft front rows)
#pragma unroll
    for (int nt = 0; nt < 4; ++nt) g4[nt] = z4;
#pragma unroll
    for (int ks = 0; ks < 4; ++ks) {
        short8 af = *(const short8*)&xs[ar0 + cr][ks * 32 + fr];
#pragma unroll
        for (int nt = 0; nt < 4; ++nt) {
            short8 bf = *(const short8*)&W3b[(size_t)(chf + nt * 16 + cr) * DD + ks * 32 + fr];
            g4[nt] = __builtin_amdgcn_mfma_f32_16x16x32_bf16(af, bf, g4[nt], 0, 0, 0);
        }
    }
#pragma unroll
    for (int nt = 0; nt < 4; ++nt)
#pragma unroll
        for (int r = 0; r < 4; ++r)
            sft[(ar0 + rr4 + r) * 136 + chf + nt * 16 + cr] = f2bf(silu_f(g4[nt][r]));
    __syncthreads();

    // GEMM2 (W4) + residual -> out (masked)
#pragma unroll
    for (int nt = 0; nt < 4; ++nt) g4[nt] = z4;
#pragma unroll
    for (int ks = 0; ks < 4; ++ks) {
        short8 af = *(const short8*)&sft[(ar0 + cr) * 136 + ks * 32 + fr];
#pragma unroll
        for (int nt = 0; nt < 4; ++nt) {
            short8 bf = *(const short8*)&W4b[(size_t)(chf + nt * 16 + cr) * DD + ks * 32 + fr];
            g4[nt] = __builtin_amdgcn_mfma_f32_16x16x32_bf16(af, bf, g4[nt], 0, 0, 0);
        }
    }
#pragma unroll
    for (int nt = 0; nt < 4; ++nt)
#pragma unroll
        for (int r = 0; r < 4; ++r) {
            int rr = ar0 + rr4 + r;
            if (rr < len)
                out[(size_t)(r0c + rr) * DD + chf + nt * 16 + cr] = xk[nt][r] + silu_f(g4[nt][r]);
        }
}

extern "C" void kernel_launch(void* const* d_in, const int* in_sizes, int n_in,
                              void* d_out, int out_size, void* d_ws, size_t ws_size,
                              hipStream_t stream) {
    const float* x      = (const float*)d_in[0];
    const float* kdr    = (const float*)d_in[1];
    const float* damp   = (const float*)d_in[2];
    const int*   batch  = (const int*)d_in[3];
    const float* dp     = (const float*)d_in[4];
    const float* W_pre1 = (const float*)d_in[5];
    const float* W_pre2 = (const float*)d_in[6];
    const float* gamma  = (const float*)d_in[7];
    const float* beta   = (const float*)d_in[8];
    const float* W_up   = (const float*)d_in[9];
    const float* W_upd1 = (const float*)d_in[10];
    const float* W_upd2 = (const float*)d_in[11];
    float* out = (float*)d_out;

    char* w = (char*)d_ws;
    ushort_t* Wb       = (ushort_t*)w;                     // 64 KiB used (W3b|W4b)
    int*      starts_g = (int*)(w + 65536);                // 33 ints
    size_t o = 131072;
    ushort_t* trig_rm = (ushort_t*)(w + o);  o += (size_t)NN * 128 * 2;       // 4 MB
    ushort_t* trigTb  = (ushort_t*)(w + o);  o += (size_t)NN * 128 * 2;       // 4 MB
    ushort_t* xresTb  = (ushort_t*)(w + o);  o += (size_t)NN * 128 * 2;       // 4 MB
    ushort_t* SFTb    = (ushort_t*)(w + o);  o += (size_t)NB * 128 * 128 * 2; // 1 MB

    hipLaunchKernelGGL(kB_pre, dim3(9 + NN / 16), dim3(256), 0, stream,
                       x, W_pre1, W_pre2, W_upd1, W_upd2, gamma, beta,
                       kdr, damp, batch, Wb, starts_g, trig_rm, trigTb, xresTb);
    hipLaunchKernelGGL(kS_scatter, dim3(NB * 32), dim3(128), 0, stream,
                       starts_g, xresTb, trigTb, dp, W_up, SFTb);
    hipLaunchKernelGGL(kD_post, dim3(576), dim3(256), 0, stream,
                       x, starts_g, trig_rm, SFTb, Wb, out);
}

// Round 19
// 63.792 us; speedup vs baseline: 1.1362x; 1.0052x over previous
//
#include <hip/hip_runtime.h>
#include <stdint.h>

#define NN 16384
#define KK 64
#define DD 128
#define PP 8
#define NB 32
#define CH 64
#define CHD 32

typedef unsigned short ushort_t;
typedef __attribute__((ext_vector_type(8))) short short8;
typedef __attribute__((ext_vector_type(4))) float f32x4;

__device__ __forceinline__ ushort_t f2bf(float x) {
    unsigned u = __float_as_uint(x);
    u += 0x7fffu + ((u >> 16) & 1u);     // round-to-nearest-even
    return (ushort_t)(u >> 16);
}
__device__ __forceinline__ float silu_f(float v) { return v / (1.0f + __expf(-v)); }

// bf16 MFMA B-fragment straight from an f32 weight matrix (L2-hot)
__device__ __forceinline__ short8 ldWf(const float* __restrict__ W, int row, int col) {
    float4 a = *(const float4*)&W[(size_t)row * DD + col];
    float4 b = *(const float4*)&W[(size_t)row * DD + col + 4];
    short8 v;
    v[0] = (short)f2bf(a.x); v[1] = (short)f2bf(a.y);
    v[2] = (short)f2bf(a.z); v[3] = (short)f2bf(a.w);
    v[4] = (short)f2bf(b.x); v[5] = (short)f2bf(b.y);
    v[6] = (short)f2bf(b.z); v[7] = (short)f2bf(b.w);
    return v;
}

// ---------------- kB: [aux] + pre-MLP + LN + trig + blocked transposes ------
// main: 256 threads, 16-row tile, 1024 blocks (4/CU). No trig_rm output.
__global__ __launch_bounds__(256, 4) void kB_pre(
        const float* __restrict__ x, const float* __restrict__ W1,
        const float* __restrict__ W2, const float* __restrict__ W3,
        const float* __restrict__ W4, const float* __restrict__ gamma,
        const float* __restrict__ beta, const float* __restrict__ kdr,
        const float* __restrict__ damp, const int* __restrict__ batch,
        ushort_t* __restrict__ Wb, int* __restrict__ starts_g,
        ushort_t* __restrict__ trigTb, ushort_t* __restrict__ xresTb) {
    __shared__ __align__(16) ushort_t xsb[16][136];   // x bf16, later trig tile
    __shared__ __align__(16) ushort_t t1b[16][136];   // t1, later LN(xres) bf16
    __shared__ float2 lnp[16][4];
    const int bid = blockIdx.x;

    if (bid < 8) {      // aux: W3/W4 -> Wb bf16 for kD
        int w = bid;
        const float* s = ((w >> 2) == 0 ? W3 : W4) + (w & 3) * 4096;
        ushort_t* d = Wb + (size_t)(w >> 2) * 16384 + (w & 3) * 4096;
        for (int i = threadIdx.x; i < 4096; i += 256) d[i] = f2bf(s[i]);
        return;
    }
    if (bid == 8) {     // aux: segment starts for kS/kD
        const int t = threadIdx.x;
        if (t <= NB) {
            int lo;
            if (t == NB) lo = NN;
            else {
                lo = 0; int hi = NN;
                while (lo < hi) { int mid = (lo + hi) >> 1; if (batch[mid] < t) lo = mid + 1; else hi = mid; }
            }
            starts_g[t] = lo;
        }
        return;
    }

    const int t = threadIdx.x, lane = t & 63, wv = t >> 6;   // wv 0..3
    const int ci = bid - 9;
    const int n0 = ci * 16;
    const int chf = wv * 32;              // column 32-slice per wave
    const int fr = (lane >> 4) * 8, cr = lane & 15, rr4 = (lane >> 4) * 4;

    // prefetch kdr/damp (hides under GEMMs)
    float2 kvp[2], dvp[2];
#pragma unroll
    for (int q = 0; q < 2; ++q) {
        int i = t + q * 256;
        int r = i >> 5, kk = (i & 31) * 2;
        kvp[q] = *(const float2*)&kdr[(size_t)(n0 + r) * KK + kk];
        dvp[q] = *(const float2*)&damp[(size_t)(n0 + r) * KK + kk];
    }
    {   // stage x -> bf16 (16 rows x 128 cols)
        const float4* src = (const float4*)(x + (size_t)n0 * DD);
        float4 v0 = src[t * 2], v1 = src[t * 2 + 1];
        int r = t >> 4, c = (t & 15) << 3;
        short8 pk;
        pk[0] = (short)f2bf(v0.x); pk[1] = (short)f2bf(v0.y);
        pk[2] = (short)f2bf(v0.z); pk[3] = (short)f2bf(v0.w);
        pk[4] = (short)f2bf(v1.x); pk[5] = (short)f2bf(v1.y);
        pk[6] = (short)f2bf(v1.z); pk[7] = (short)f2bf(v1.w);
        *(short8*)&xsb[r][c] = pk;
    }
    __syncthreads();

    f32x4 acc[2];
    const f32x4 z4 = {0.f, 0.f, 0.f, 0.f};

    // GEMM1 (W1 on-the-fly bf16)
#pragma unroll
    for (int nt = 0; nt < 2; ++nt) acc[nt] = z4;
#pragma unroll
    for (int ks = 0; ks < 4; ++ks) {
        short8 af = *(const short8*)&xsb[cr][ks * 32 + fr];
#pragma unroll
        for (int nt = 0; nt < 2; ++nt) {
            short8 bf = ldWf(W1, chf + nt * 16 + cr, ks * 32 + fr);
            acc[nt] = __builtin_amdgcn_mfma_f32_16x16x32_bf16(af, bf, acc[nt], 0, 0, 0);
        }
    }
#pragma unroll
    for (int nt = 0; nt < 2; ++nt)
#pragma unroll
        for (int r = 0; r < 4; ++r)
            t1b[rr4 + r][chf + nt * 16 + cr] = f2bf(silu_f(acc[nt][r]));
    __syncthreads();

    // GEMM2 (W2 on-the-fly) + trig tile + residual + LN partials
#pragma unroll
    for (int nt = 0; nt < 2; ++nt) acc[nt] = z4;
#pragma unroll
    for (int ks = 0; ks < 4; ++ks) {
        short8 af = *(const short8*)&t1b[cr][ks * 32 + fr];
#pragma unroll
        for (int nt = 0; nt < 2; ++nt) {
            short8 bf = ldWf(W2, chf + nt * 16 + cr, ks * 32 + fr);
            acc[nt] = __builtin_amdgcn_mfma_f32_16x16x32_bf16(af, bf, acc[nt], 0, 0, 0);
        }
    }
#pragma unroll
    for (int q = 0; q < 2; ++q) {
        int i = t + q * 256;
        int r = i >> 5, kk = (i & 31) * 2;
        float s0, c0, s1, c1;
        __sincosf(kvp[q].x, &s0, &c0);
        __sincosf(kvp[q].y, &s1, &c1);
        xsb[r][kk]      = f2bf(c0 * dvp[q].x);
        xsb[r][kk + 1]  = f2bf(c1 * dvp[q].y);
        xsb[r][64 + kk]     = f2bf(s0 * dvp[q].x);
        xsb[r][64 + kk + 1] = f2bf(s1 * dvp[q].y);
    }
    float g[2], be[2];
#pragma unroll
    for (int nt = 0; nt < 2; ++nt) {
        g[nt] = gamma[chf + nt * 16 + cr];
        be[nt] = beta[chf + nt * 16 + cr];
    }
#pragma unroll
    for (int r = 0; r < 4; ++r) {
        int row = n0 + rr4 + r;
        float s = 0.f, sq = 0.f;
#pragma unroll
        for (int nt = 0; nt < 2; ++nt) {
            float v = x[(size_t)row * DD + chf + nt * 16 + cr] + silu_f(acc[nt][r]);
            acc[nt][r] = v;
            s += v; sq += v * v;
        }
#pragma unroll
        for (int off = 1; off < 16; off <<= 1) {
            s += __shfl_xor(s, off);
            sq += __shfl_xor(sq, off);
        }
        if (cr == 0) {
            float2 p; p.x = s; p.y = sq;
            lnp[rr4 + r][wv] = p;
        }
    }
    __syncthreads();

    // LN finalize -> t1b
#pragma unroll
    for (int r = 0; r < 4; ++r) {
        int row = rr4 + r;
        float2 a0 = lnp[row][0], a1 = lnp[row][1], a2 = lnp[row][2], a3 = lnp[row][3];
        float s = a0.x + a1.x + a2.x + a3.x, sq = a0.y + a1.y + a2.y + a3.y;
        float mu = s * (1.0f / 128.0f);
        float var = sq * (1.0f / 128.0f) - mu * mu;
        float rs = rsqrtf(var + 1e-5f);
#pragma unroll
        for (int nt = 0; nt < 2; ++nt)
            t1b[row][chf + nt * 16 + cr] = f2bf((acc[nt][r] - mu) * rs * g[nt] + be[nt]);
    }
    __syncthreads();

    // blocked transposed writes (this 16-row quarter of a 64-row chunk)
    {
        int m = t >> 1, hh = (t & 1) * 8;
        size_t base = (size_t)(ci >> 2) * 8192 + (size_t)m * 64 + (ci & 3) * 16 + hh;
        short8 v;
#pragma unroll
        for (int j = 0; j < 8; ++j) v[j] = (short)xsb[hh + j][m];
        *(short8*)&trigTb[base] = v;
#pragma unroll
        for (int j = 0; j < 8; ++j) v[j] = (short)t1b[hh + j][m];
        *(short8*)&xresTb[base] = v;
    }
}

// ---------------- kS: per-(segment, d-group, m-half) scatter -> SFTb --------
// 512 blocks x 256 threads (4/CU), LDS-staged contiguous, XCD-local.
__global__ __launch_bounds__(256, 4) void kS_scatter(
        const int* __restrict__ starts_g,
        const ushort_t* __restrict__ xresTb, const ushort_t* __restrict__ trigTb,
        const float* __restrict__ dp, const float* __restrict__ wup,
        ushort_t* __restrict__ SFTb) {
    __shared__ __align__(16) ushort_t xt[16][72];
    __shared__ __align__(16) ushort_t tt[64][72];
    __shared__ int seg2[2];
    const int b = blockIdx.x & 31, g2 = blockIdx.x >> 5;     // g2 0..15
    const int d0 = (g2 & 7) * 16, mh = (g2 >> 3) * 64;
    const int t = threadIdx.x, lane = t & 63, wv = t >> 6;   // wv 0..3

    if (t < 2) seg2[t] = starts_g[b + t];
    __syncthreads();
    const int segs = seg2[0], sege = seg2[1];

    const int fr = (lane >> 4) * 8, cr = lane & 15, rr4 = (lane >> 4) * 4;
    const f32x4 z4 = {0.f, 0.f, 0.f, 0.f};
    f32x4 acc = z4;

    for (int r0 = segs & ~(CH - 1); r0 < sege; r0 += CH) {
        int lo = segs - r0; if (lo < 0) lo = 0;
        int hi = sege - r0; if (hi > CH) hi = CH;
        const size_t cb = (size_t)(r0 >> 6) * 8192;
        for (int i = t; i < 160; i += 256) {
            int row = i >> 1, h = (i & 1) * 32;
            const ushort_t* src = (row < 16 ? xresTb + cb + (size_t)(d0 + row) * 64
                                            : trigTb + cb + (size_t)(mh + row - 16) * 64) + h;
            ushort_t* dst = (row < 16 ? &xt[row][h] : &tt[row - 16][h]);
            if (lo == 0 && hi == CH) {
#pragma unroll
                for (int q = 0; q < 4; ++q) *(short8*)(dst + q * 8) = *(const short8*)(src + q * 8);
            } else {
                for (int j = 0; j < 32; ++j) { int c = h + j; dst[j] = (c >= lo && c < hi) ? src[j] : (ushort_t)0; }
            }
        }
        __syncthreads();
#pragma unroll
        for (int ks = 0; ks < 2; ++ks) {
            short8 af = *(const short8*)&xt[cr][ks * 32 + fr];
            short8 bf = *(const short8*)&tt[wv * 16 + cr][ks * 32 + fr];
            acc = __builtin_amdgcn_mfma_f32_16x16x32_bf16(af, bf, acc, 0, 0, 0);
        }
        __syncthreads();
    }

    // kfilter + bf16 store
    const int m = mh + wv * 16 + cr;
    const int k = m & 63;
    float4 p0 = *(const float4*)&dp[k * PP];
    float4 p1 = *(const float4*)&dp[k * PP + 4];
#pragma unroll
    for (int r = 0; r < 4; ++r) {
        int d = d0 + rr4 + r;
        float4 w0 = *(const float4*)&wup[d * PP];
        float4 w1 = *(const float4*)&wup[d * PP + 4];
        float kf = p0.x * w0.x + p0.y * w0.y + p0.z * w0.z + p0.w * w0.w
                 + p1.x * w1.x + p1.y * w1.y + p1.z * w1.z + p1.w * w1.w;
        SFTb[((size_t)b * 128 + d) * 128 + m] = f2bf(acc[r] * kf);
    }
}

// ---------------- kD: gather (trig recomputed in-reg) + post-MLP -> out -----
__global__ __launch_bounds__(256, 3) void kD_post(
        const float* __restrict__ x, const int* __restrict__ starts_g,
        const float* __restrict__ kdr, const float* __restrict__ damp,
        const ushort_t* __restrict__ SFTb, const ushort_t* __restrict__ Wb,
        float* __restrict__ out) {
    __shared__ __align__(16) ushort_t sft[128 * 136];   // t1 aliases after gather
    __shared__ __align__(16) ushort_t xs[32][136];
    __shared__ int starts[NB + 1];
    __shared__ int offs[NB + 1];
    const int t = threadIdx.x, lane = t & 63, wv = t >> 6;   // wv 0..3
    const int fr = (lane >> 4) * 8, cr = lane & 15, rr4 = (lane >> 4) * 4;
    const f32x4 z4 = {0.f, 0.f, 0.f, 0.f};

    if (t < 33) starts[t] = starts_g[t];
    __syncthreads();
    if (t == 0) {
        int off = 0;
        for (int b = 0; b < NB; ++b) {
            offs[b] = off;
            off += (starts[b + 1] - starts[b] + CHD - 1) / CHD;
        }
        offs[NB] = off;
    }
    __syncthreads();
    const int nwl = offs[NB];
    const int c = (blockIdx.x & 7) * 72 + (blockIdx.x >> 3);   // XCD-local segments
    if (c >= nwl) return;
    int b = 0;
    while (offs[b + 1] <= c) ++b;
    const int r0c = starts[b] + (c - offs[b]) * CHD;
    const int len = min(CHD, starts[b + 1] - r0c);

    const int ar0 = (wv & 1) * 16;
    const int chf = (wv >> 1) * 64;
    const ushort_t* W3b = Wb;
    const ushort_t* W4b = Wb + 16384;

    // recompute gather A-fragments from kdr/damp (VALU, hides under sft stage)
    // afp[ks] covers m = ks*32+fr..+7 of stacked [cos(0..63)|sin(0..63)]:
    //   ks=0: cos(k=fr..), ks=1: cos(k=32+fr..), ks=2: sin(k=fr..), ks=3: sin(k=32+fr..)
    int nrow = r0c + ar0 + cr; if (nrow >= NN) nrow = NN - 1;
    short8 afp[4];
#pragma unroll
    for (int q = 0; q < 2; ++q) {
        int k0 = q * 32 + fr;
        float4 kv0 = *(const float4*)&kdr[(size_t)nrow * KK + k0];
        float4 kv1 = *(const float4*)&kdr[(size_t)nrow * KK + k0 + 4];
        float4 dv0 = *(const float4*)&damp[(size_t)nrow * KK + k0];
        float4 dv1 = *(const float4*)&damp[(size_t)nrow * KK + k0 + 4];
        float kv[8] = {kv0.x, kv0.y, kv0.z, kv0.w, kv1.x, kv1.y, kv1.z, kv1.w};
        float dv[8] = {dv0.x, dv0.y, dv0.z, dv0.w, dv1.x, dv1.y, dv1.z, dv1.w};
#pragma unroll
        for (int e = 0; e < 8; ++e) {
            float s, cc;
            __sincosf(kv[e], &s, &cc);
            afp[q][e]     = (short)f2bf(cc * dv[e]);
            afp[q + 2][e] = (short)f2bf(s * dv[e]);
        }
    }
    // prefetch x residual (hide under sft stage)
    float xr[4][4];
#pragma unroll
    for (int nt = 0; nt < 4; ++nt)
#pragma unroll
        for (int r = 0; r < 4; ++r) {
            int row = r0c + ar0 + rr4 + r; if (row >= NN) row = NN - 1;
            xr[nt][r] = x[(size_t)row * DD + chf + nt * 16 + cr];
        }

    // stage SFTb[b] (32KB contiguous)
    {
        const ushort_t* srcS = SFTb + (size_t)b * 16384;
        for (int i = t; i < 2048; i += 256) {
            int r = i >> 4, cc = (i & 15) * 8;
            *(short8*)&sft[r * 136 + cc] = *(const short8*)(srcS + r * 128 + cc);
        }
    }
    __syncthreads();

    // gather
    f32x4 g4[4];
#pragma unroll
    for (int nt = 0; nt < 4; ++nt) g4[nt] = z4;
#pragma unroll
    for (int ks = 0; ks < 4; ++ks) {
#pragma unroll
        for (int nt = 0; nt < 4; ++nt) {
            short8 bf = *(const short8*)&sft[(chf + nt * 16 + cr) * 136 + ks * 32 + fr];
            g4[nt] = __builtin_amdgcn_mfma_f32_16x16x32_bf16(afp[ks], bf, g4[nt], 0, 0, 0);
        }
    }

    // xg = x + msg
    float xk[4][4];
#pragma unroll
    for (int nt = 0; nt < 4; ++nt)
#pragma unroll
        for (int r = 0; r < 4; ++r) {
            int rr = ar0 + rr4 + r;
            float xv = xr[nt][r] + g4[nt][r];
            xk[nt][r] = xv;
            xs[rr][chf + nt * 16 + cr] = f2bf(xv);
        }
    __syncthreads();   // sft gather reads done -> t1 alias safe; xs ready

    // GEMM1 (W3) -> t1 (aliases sft front rows)
#pragma unroll
    for (int nt = 0; nt < 4; ++nt) g4[nt] = z4;
#pragma unroll
    for (int ks = 0; ks < 4; ++ks) {
        short8 af = *(const short8*)&xs[ar0 + cr][ks * 32 + fr];
#pragma unroll
        for (int nt = 0; nt < 4; ++nt) {
            short8 bf = *(const short8*)&W3b[(size_t)(chf + nt * 16 + cr) * DD + ks * 32 + fr];
            g4[nt] = __builtin_amdgcn_mfma_f32_16x16x32_bf16(af, bf, g4[nt], 0, 0, 0);
        }
    }
#pragma unroll
    for (int nt = 0; nt < 4; ++nt)
#pragma unroll
        for (int r = 0; r < 4; ++r)
            sft[(ar0 + rr4 + r) * 136 + chf + nt * 16 + cr] = f2bf(silu_f(g4[nt][r]));
    __syncthreads();

    // GEMM2 (W4) + residual -> out (masked)
#pragma unroll
    for (int nt = 0; nt < 4; ++nt) g4[nt] = z4;
#pragma unroll
    for (int ks = 0; ks < 4; ++ks) {
        short8 af = *(const short8*)&sft[(ar0 + cr) * 136 + ks * 32 + fr];
#pragma unroll
        for (int nt = 0; nt < 4; ++nt) {
            short8 bf = *(const short8*)&W4b[(size_t)(chf + nt * 16 + cr) * DD + ks * 32 + fr];
            g4[nt] = __builtin_amdgcn_mfma_f32_16x16x32_bf16(af, bf, g4[nt], 0, 0, 0);
        }
    }
#pragma unroll
    for (int nt = 0; nt < 4; ++nt)
#pragma unroll
        for (int r = 0; r < 4; ++r) {
            int rr = ar0 + rr4 + r;
            if (rr < len)
                out[(size_t)(r0c + rr) * DD + chf + nt * 16 + cr] = xk[nt][r] + silu_f(g4[nt][r]);
        }
}

extern "C" void kernel_launch(void* const* d_in, const int* in_sizes, int n_in,
                              void* d_out, int out_size, void* d_ws, size_t ws_size,
                              hipStream_t stream) {
    const float* x      = (const float*)d_in[0];
    const float* kdr    = (const float*)d_in[1];
    const float* damp   = (const float*)d_in[2];
    const int*   batch  = (const int*)d_in[3];
    const float* dp     = (const float*)d_in[4];
    const float* W_pre1 = (const float*)d_in[5];
    const float* W_pre2 = (const float*)d_in[6];
    const float* gamma  = (const float*)d_in[7];
    const float* beta   = (const float*)d_in[8];
    const float* W_up   = (const float*)d_in[9];
    const float* W_upd1 = (const float*)d_in[10];
    const float* W_upd2 = (const float*)d_in[11];
    float* out = (float*)d_out;

    char* w = (char*)d_ws;
    ushort_t* Wb       = (ushort_t*)w;                     // 64 KiB used (W3b|W4b)
    int*      starts_g = (int*)(w + 65536);                // 33 ints
    size_t o = 131072;
    ushort_t* trigTb  = (ushort_t*)(w + o);  o += (size_t)NN * 128 * 2;       // 4 MB
    ushort_t* xresTb  = (ushort_t*)(w + o);  o += (size_t)NN * 128 * 2;       // 4 MB
    ushort_t* SFTb    = (ushort_t*)(w + o);  o += (size_t)NB * 128 * 128 * 2; // 1 MB

    hipLaunchKernelGGL(kB_pre, dim3(9 + NN / 16), dim3(256), 0, stream,
                       x, W_pre1, W_pre2, W_upd1, W_upd2, gamma, beta,
                       kdr, damp, batch, Wb, starts_g, trigTb, xresTb);
    hipLaunchKernelGGL(kS_scatter, dim3(NB * 16), dim3(256), 0, stream,
                       starts_g, xresTb, trigTb, dp, W_up, SFTb);
    hipLaunchKernelGGL(kD_post, dim3(576), dim3(256), 0, stream,
                       x, starts_g, kdr, damp, SFTb, Wb, out);
}

// Round 20
// 62.948 us; speedup vs baseline: 1.1514x; 1.0134x over previous
//
#include <hip/hip_runtime.h>
#include <stdint.h>

#define NN 16384
#define KK 64
#define DD 128
#define PP 8
#define NB 32
#define CH 64
#define CHD 32

typedef unsigned short ushort_t;
typedef __attribute__((ext_vector_type(8))) short short8;
typedef __attribute__((ext_vector_type(4))) float f32x4;

__device__ __forceinline__ ushort_t f2bf(float x) {
    unsigned u = __float_as_uint(x);
    u += 0x7fffu + ((u >> 16) & 1u);     // round-to-nearest-even
    return (ushort_t)(u >> 16);
}
__device__ __forceinline__ float silu_f(float v) { return v / (1.0f + __expf(-v)); }

// bf16 MFMA B-fragment straight from an f32 weight matrix (L2-hot)
__device__ __forceinline__ short8 ldWf(const float* __restrict__ W, int row, int col) {
    float4 a = *(const float4*)&W[(size_t)row * DD + col];
    float4 b = *(const float4*)&W[(size_t)row * DD + col + 4];
    short8 v;
    v[0] = (short)f2bf(a.x); v[1] = (short)f2bf(a.y);
    v[2] = (short)f2bf(a.z); v[3] = (short)f2bf(a.w);
    v[4] = (short)f2bf(b.x); v[5] = (short)f2bf(b.y);
    v[6] = (short)f2bf(b.z); v[7] = (short)f2bf(b.w);
    return v;
}

// ---------------- kB: [aux] + pre-MLP + LN + trig + blocked transposes ------
// main: 256 threads, 16-row tile, 1024 blocks (4/CU).
__global__ __launch_bounds__(256, 4) void kB_pre(
        const float* __restrict__ x, const float* __restrict__ W1,
        const float* __restrict__ W2, const float* __restrict__ W3,
        const float* __restrict__ W4, const float* __restrict__ gamma,
        const float* __restrict__ beta, const float* __restrict__ kdr,
        const float* __restrict__ damp, const int* __restrict__ batch,
        ushort_t* __restrict__ Wb, int* __restrict__ starts_g,
        ushort_t* __restrict__ trig_rm, ushort_t* __restrict__ trigTb,
        ushort_t* __restrict__ xresTb) {
    __shared__ __align__(16) ushort_t xsb[16][136];   // x bf16, later trig tile
    __shared__ __align__(16) ushort_t t1b[16][136];   // t1, later LN(xres) bf16
    __shared__ float2 lnp[16][4];
    const int bid = blockIdx.x;

    if (bid < 8) {      // aux: W3/W4 -> Wb bf16 for kD
        int w = bid;
        const float* s = ((w >> 2) == 0 ? W3 : W4) + (w & 3) * 4096;
        ushort_t* d = Wb + (size_t)(w >> 2) * 16384 + (w & 3) * 4096;
        for (int i = threadIdx.x; i < 4096; i += 256) d[i] = f2bf(s[i]);
        return;
    }
    if (bid == 8) {     // aux: segment starts for kS/kD
        const int t = threadIdx.x;
        if (t <= NB) {
            int lo;
            if (t == NB) lo = NN;
            else {
                lo = 0; int hi = NN;
                while (lo < hi) { int mid = (lo + hi) >> 1; if (batch[mid] < t) lo = mid + 1; else hi = mid; }
            }
            starts_g[t] = lo;
        }
        return;
    }

    const int t = threadIdx.x, lane = t & 63, wv = t >> 6;   // wv 0..3
    const int ci = bid - 9;
    const int n0 = ci * 16;
    const int chf = wv * 32;              // column 32-slice per wave
    const int fr = (lane >> 4) * 8, cr = lane & 15, rr4 = (lane >> 4) * 4;

    // prefetch kdr/damp (hides under GEMMs)
    float2 kvp[2], dvp[2];
#pragma unroll
    for (int q = 0; q < 2; ++q) {
        int i = t + q * 256;
        int r = i >> 5, kk = (i & 31) * 2;
        kvp[q] = *(const float2*)&kdr[(size_t)(n0 + r) * KK + kk];
        dvp[q] = *(const float2*)&damp[(size_t)(n0 + r) * KK + kk];
    }
    {   // stage x -> bf16 (16 rows x 128 cols)
        const float4* src = (const float4*)(x + (size_t)n0 * DD);
        float4 v0 = src[t * 2], v1 = src[t * 2 + 1];
        int r = t >> 4, c = (t & 15) << 3;
        short8 pk;
        pk[0] = (short)f2bf(v0.x); pk[1] = (short)f2bf(v0.y);
        pk[2] = (short)f2bf(v0.z); pk[3] = (short)f2bf(v0.w);
        pk[4] = (short)f2bf(v1.x); pk[5] = (short)f2bf(v1.y);
        pk[6] = (short)f2bf(v1.z); pk[7] = (short)f2bf(v1.w);
        *(short8*)&xsb[r][c] = pk;
    }
    __syncthreads();

    f32x4 acc[2];
    const f32x4 z4 = {0.f, 0.f, 0.f, 0.f};

    // GEMM1 (W1 on-the-fly bf16)
#pragma unroll
    for (int nt = 0; nt < 2; ++nt) acc[nt] = z4;
#pragma unroll
    for (int ks = 0; ks < 4; ++ks) {
        short8 af = *(const short8*)&xsb[cr][ks * 32 + fr];
#pragma unroll
        for (int nt = 0; nt < 2; ++nt) {
            short8 bf = ldWf(W1, chf + nt * 16 + cr, ks * 32 + fr);
            acc[nt] = __builtin_amdgcn_mfma_f32_16x16x32_bf16(af, bf, acc[nt], 0, 0, 0);
        }
    }
#pragma unroll
    for (int nt = 0; nt < 2; ++nt)
#pragma unroll
        for (int r = 0; r < 4; ++r)
            t1b[rr4 + r][chf + nt * 16 + cr] = f2bf(silu_f(acc[nt][r]));
    __syncthreads();

    // GEMM2 (W2 on-the-fly) + trig + residual + LN partials
#pragma unroll
    for (int nt = 0; nt < 2; ++nt) acc[nt] = z4;
#pragma unroll
    for (int ks = 0; ks < 4; ++ks) {
        short8 af = *(const short8*)&t1b[cr][ks * 32 + fr];
#pragma unroll
        for (int nt = 0; nt < 2; ++nt) {
            short8 bf = ldWf(W2, chf + nt * 16 + cr, ks * 32 + fr);
            acc[nt] = __builtin_amdgcn_mfma_f32_16x16x32_bf16(af, bf, acc[nt], 0, 0, 0);
        }
    }
#pragma unroll
    for (int q = 0; q < 2; ++q) {
        int i = t + q * 256;
        int r = i >> 5, kk = (i & 31) * 2;
        float s0, c0, s1, c1;
        __sincosf(kvp[q].x, &s0, &c0);
        __sincosf(kvp[q].y, &s1, &c1);
        ushort_t rc0 = f2bf(c0 * dvp[q].x), rc1 = f2bf(c1 * dvp[q].y);
        ushort_t is0 = f2bf(s0 * dvp[q].x), is1 = f2bf(s1 * dvp[q].y);
        xsb[r][kk] = rc0; xsb[r][kk + 1] = rc1;
        xsb[r][64 + kk] = is0; xsb[r][64 + kk + 1] = is1;
        ushort2 a; a.x = rc0; a.y = rc1;
        ushort2 b; b.x = is0; b.y = is1;
        *(ushort2*)&trig_rm[(size_t)(n0 + r) * 128 + kk] = a;
        *(ushort2*)&trig_rm[(size_t)(n0 + r) * 128 + 64 + kk] = b;
    }
    float g[2], be[2];
#pragma unroll
    for (int nt = 0; nt < 2; ++nt) {
        g[nt] = gamma[chf + nt * 16 + cr];
        be[nt] = beta[chf + nt * 16 + cr];
    }
#pragma unroll
    for (int r = 0; r < 4; ++r) {
        int row = n0 + rr4 + r;
        float s = 0.f, sq = 0.f;
#pragma unroll
        for (int nt = 0; nt < 2; ++nt) {
            float v = x[(size_t)row * DD + chf + nt * 16 + cr] + silu_f(acc[nt][r]);
            acc[nt][r] = v;
            s += v; sq += v * v;
        }
#pragma unroll
        for (int off = 1; off < 16; off <<= 1) {
            s += __shfl_xor(s, off);
            sq += __shfl_xor(sq, off);
        }
        if (cr == 0) {
            float2 p; p.x = s; p.y = sq;
            lnp[rr4 + r][wv] = p;
        }
    }
    __syncthreads();

    // LN finalize -> t1b
#pragma unroll
    for (int r = 0; r < 4; ++r) {
        int row = rr4 + r;
        float2 a0 = lnp[row][0], a1 = lnp[row][1], a2 = lnp[row][2], a3 = lnp[row][3];
        float s = a0.x + a1.x + a2.x + a3.x, sq = a0.y + a1.y + a2.y + a3.y;
        float mu = s * (1.0f / 128.0f);
        float var = sq * (1.0f / 128.0f) - mu * mu;
        float rs = rsqrtf(var + 1e-5f);
#pragma unroll
        for (int nt = 0; nt < 2; ++nt)
            t1b[row][chf + nt * 16 + cr] = f2bf((acc[nt][r] - mu) * rs * g[nt] + be[nt]);
    }
    __syncthreads();

    // blocked transposed writes (this 16-row quarter of a 64-row chunk)
    {
        int m = t >> 1, hh = (t & 1) * 8;
        size_t base = (size_t)(ci >> 2) * 8192 + (size_t)m * 64 + (ci & 3) * 16 + hh;
        short8 v;
#pragma unroll
        for (int j = 0; j < 8; ++j) v[j] = (short)xsb[hh + j][m];
        *(short8*)&trigTb[base] = v;
#pragma unroll
        for (int j = 0; j < 8; ++j) v[j] = (short)t1b[hh + j][m];
        *(short8*)&xresTb[base] = v;
    }
}

// ---------------- kS: per-(segment, d-group, m-half) scatter -> SFTb --------
// 512 blocks x 256 threads (4/CU), LDS-staged contiguous, XCD-local.
__global__ __launch_bounds__(256, 4) void kS_scatter(
        const int* __restrict__ starts_g,
        const ushort_t* __restrict__ xresTb, const ushort_t* __restrict__ trigTb,
        const float* __restrict__ dp, const float* __restrict__ wup,
        ushort_t* __restrict__ SFTb) {
    __shared__ __align__(16) ushort_t xt[16][72];
    __shared__ __align__(16) ushort_t tt[64][72];
    __shared__ int seg2[2];
    const int b = blockIdx.x & 31, g2 = blockIdx.x >> 5;     // g2 0..15
    const int d0 = (g2 & 7) * 16, mh = (g2 >> 3) * 64;
    const int t = threadIdx.x, lane = t & 63, wv = t >> 6;   // wv 0..3

    if (t < 2) seg2[t] = starts_g[b + t];
    __syncthreads();
    const int segs = seg2[0], sege = seg2[1];

    const int fr = (lane >> 4) * 8, cr = lane & 15, rr4 = (lane >> 4) * 4;
    const f32x4 z4 = {0.f, 0.f, 0.f, 0.f};
    f32x4 acc = z4;

    for (int r0 = segs & ~(CH - 1); r0 < sege; r0 += CH) {
        int lo = segs - r0; if (lo < 0) lo = 0;
        int hi = sege - r0; if (hi > CH) hi = CH;
        const size_t cb = (size_t)(r0 >> 6) * 8192;
        for (int i = t; i < 160; i += 256) {
            int row = i >> 1, h = (i & 1) * 32;
            const ushort_t* src = (row < 16 ? xresTb + cb + (size_t)(d0 + row) * 64
                                            : trigTb + cb + (size_t)(mh + row - 16) * 64) + h;
            ushort_t* dst = (row < 16 ? &xt[row][h] : &tt[row - 16][h]);
            if (lo == 0 && hi == CH) {
#pragma unroll
                for (int q = 0; q < 4; ++q) *(short8*)(dst + q * 8) = *(const short8*)(src + q * 8);
            } else {
                for (int j = 0; j < 32; ++j) { int c = h + j; dst[j] = (c >= lo && c < hi) ? src[j] : (ushort_t)0; }
            }
        }
        __syncthreads();
#pragma unroll
        for (int ks = 0; ks < 2; ++ks) {
            short8 af = *(const short8*)&xt[cr][ks * 32 + fr];
            short8 bf = *(const short8*)&tt[wv * 16 + cr][ks * 32 + fr];
            acc = __builtin_amdgcn_mfma_f32_16x16x32_bf16(af, bf, acc, 0, 0, 0);
        }
        __syncthreads();
    }

    // kfilter + bf16 store
    const int m = mh + wv * 16 + cr;
    const int k = m & 63;
    float4 p0 = *(const float4*)&dp[k * PP];
    float4 p1 = *(const float4*)&dp[k * PP + 4];
#pragma unroll
    for (int r = 0; r < 4; ++r) {
        int d = d0 + rr4 + r;
        float4 w0 = *(const float4*)&wup[d * PP];
        float4 w1 = *(const float4*)&wup[d * PP + 4];
        float kf = p0.x * w0.x + p0.y * w0.y + p0.z * w0.z + p0.w * w0.w
                 + p1.x * w1.x + p1.y * w1.y + p1.z * w1.z + p1.w * w1.w;
        SFTb[((size_t)b * 128 + d) * 128 + m] = f2bf(acc[r] * kf);
    }
}

// ---------------- kD: gather + post-MLP + residual -> out (32-row chunks) ---
__global__ __launch_bounds__(256, 3) void kD_post(
        const float* __restrict__ x, const int* __restrict__ starts_g,
        const ushort_t* __restrict__ trig_rm, const ushort_t* __restrict__ SFTb,
        const ushort_t* __restrict__ Wb, float* __restrict__ out) {
    __shared__ __align__(16) ushort_t sft[128 * 136];   // t1 aliases after gather
    __shared__ __align__(16) ushort_t xs[32][136];
    __shared__ int starts[NB + 1];
    __shared__ int offs[NB + 1];
    const int t = threadIdx.x, lane = t & 63, wv = t >> 6;   // wv 0..3
    const int fr = (lane >> 4) * 8, cr = lane & 15, rr4 = (lane >> 4) * 4;
    const f32x4 z4 = {0.f, 0.f, 0.f, 0.f};

    if (t < 33) starts[t] = starts_g[t];
    __syncthreads();
    if (t == 0) {
        int off = 0;
        for (int b = 0; b < NB; ++b) {
            offs[b] = off;
            off += (starts[b + 1] - starts[b] + CHD - 1) / CHD;
        }
        offs[NB] = off;
    }
    __syncthreads();
    const int nwl = offs[NB];
    const int c = (blockIdx.x & 7) * 72 + (blockIdx.x >> 3);   // XCD-local segments
    if (c >= nwl) return;
    int b = 0;
    while (offs[b + 1] <= c) ++b;
    const int r0c = starts[b] + (c - offs[b]) * CHD;
    const int len = min(CHD, starts[b + 1] - r0c);

    const int ar0 = (wv & 1) * 16;
    const int chf = (wv >> 1) * 64;
    const ushort_t* W3b = Wb;
    const ushort_t* W4b = Wb + 16384;

    // prefetch gather A-fragments + x residual (hide under sft stage)
    int nrow = r0c + ar0 + cr; if (nrow >= NN) nrow = NN - 1;
    short8 afp[4];
#pragma unroll
    for (int ks = 0; ks < 4; ++ks)
        afp[ks] = *(const short8*)&trig_rm[(size_t)nrow * 128 + ks * 32 + fr];
    float xr[4][4];
#pragma unroll
    for (int nt = 0; nt < 4; ++nt)
#pragma unroll
        for (int r = 0; r < 4; ++r) {
            int row = r0c + ar0 + rr4 + r; if (row >= NN) row = NN - 1;
            xr[nt][r] = x[(size_t)row * DD + chf + nt * 16 + cr];
        }

    // stage SFTb[b] (32KB contiguous)
    {
        const ushort_t* srcS = SFTb + (size_t)b * 16384;
        for (int i = t; i < 2048; i += 256) {
            int r = i >> 4, cc = (i & 15) * 8;
            *(short8*)&sft[r * 136 + cc] = *(const short8*)(srcS + r * 128 + cc);
        }
    }
    __syncthreads();

    // gather
    f32x4 g4[4];
#pragma unroll
    for (int nt = 0; nt < 4; ++nt) g4[nt] = z4;
#pragma unroll
    for (int ks = 0; ks < 4; ++ks) {
#pragma unroll
        for (int nt = 0; nt < 4; ++nt) {
            short8 bf = *(const short8*)&sft[(chf + nt * 16 + cr) * 136 + ks * 32 + fr];
            g4[nt] = __builtin_amdgcn_mfma_f32_16x16x32_bf16(afp[ks], bf, g4[nt], 0, 0, 0);
        }
    }

    // xg = x + msg
    float xk[4][4];
#pragma unroll
    for (int nt = 0; nt < 4; ++nt)
#pragma unroll
        for (int r = 0; r < 4; ++r) {
            int rr = ar0 + rr4 + r;
            float xv = xr[nt][r] + g4[nt][r];
            xk[nt][r] = xv;
            xs[rr][chf + nt * 16 + cr] = f2bf(xv);
        }
    __syncthreads();   // sft gather reads done -> t1 alias safe; xs ready

    // GEMM1 (W3) -> t1 (aliases sft front rows)
#pragma unroll
    for (int nt = 0; nt < 4; ++nt) g4[nt] = z4;
#pragma unroll
    for (int ks = 0; ks < 4; ++ks) {
        short8 af = *(const short8*)&xs[ar0 + cr][ks * 32 + fr];
#pragma unroll
        for (int nt = 0; nt < 4; ++nt) {
            short8 bf = *(const short8*)&W3b[(size_t)(chf + nt * 16 + cr) * DD + ks * 32 + fr];
            g4[nt] = __builtin_amdgcn_mfma_f32_16x16x32_bf16(af, bf, g4[nt], 0, 0, 0);
        }
    }
#pragma unroll
    for (int nt = 0; nt < 4; ++nt)
#pragma unroll
        for (int r = 0; r < 4; ++r)
            sft[(ar0 + rr4 + r) * 136 + chf + nt * 16 + cr] = f2bf(silu_f(g4[nt][r]));
    __syncthreads();

    // GEMM2 (W4) + residual -> out (masked)
#pragma unroll
    for (int nt = 0; nt < 4; ++nt) g4[nt] = z4;
#pragma unroll
    for (int ks = 0; ks < 4; ++ks) {
        short8 af = *(const short8*)&sft[(ar0 + cr) * 136 + ks * 32 + fr];
#pragma unroll
        for (int nt = 0; nt < 4; ++nt) {
            short8 bf = *(const short8*)&W4b[(size_t)(chf + nt * 16 + cr) * DD + ks * 32 + fr];
            g4[nt] = __builtin_amdgcn_mfma_f32_16x16x32_bf16(af, bf, g4[nt], 0, 0, 0);
        }
    }
#pragma unroll
    for (int nt = 0; nt < 4; ++nt)
#pragma unroll
        for (int r = 0; r < 4; ++r) {
            int rr = ar0 + rr4 + r;
            if (rr < len)
                out[(size_t)(r0c + rr) * DD + chf + nt * 16 + cr] = xk[nt][r] + silu_f(g4[nt][r]);
        }
}

extern "C" void kernel_launch(void* const* d_in, const int* in_sizes, int n_in,
                              void* d_out, int out_size, void* d_ws, size_t ws_size,
                              hipStream_t stream) {
    const float* x      = (const float*)d_in[0];
    const float* kdr    = (const float*)d_in[1];
    const float* damp   = (const float*)d_in[2];
    const int*   batch  = (const int*)d_in[3];
    const float* dp     = (const float*)d_in[4];
    const float* W_pre1 = (const float*)d_in[5];
    const float* W_pre2 = (const float*)d_in[6];
    const float* gamma  = (const float*)d_in[7];
    const float* beta   = (const float*)d_in[8];
    const float* W_up   = (const float*)d_in[9];
    const float* W_upd1 = (const float*)d_in[10];
    const float* W_upd2 = (const float*)d_in[11];
    float* out = (float*)d_out;

    char* w = (char*)d_ws;
    ushort_t* Wb       = (ushort_t*)w;                     // 64 KiB used (W3b|W4b)
    int*      starts_g = (int*)(w + 65536);                // 33 ints
    size_t o = 131072;
    ushort_t* trig_rm = (ushort_t*)(w + o);  o += (size_t)NN * 128 * 2;       // 4 MB
    ushort_t* trigTb  = (ushort_t*)(w + o);  o += (size_t)NN * 128 * 2;       // 4 MB
    ushort_t* xresTb  = (ushort_t*)(w + o);  o += (size_t)NN * 128 * 2;       // 4 MB
    ushort_t* SFTb    = (ushort_t*)(w + o);  o += (size_t)NB * 128 * 128 * 2; // 1 MB

    hipLaunchKernelGGL(kB_pre, dim3(9 + NN / 16), dim3(256), 0, stream,
                       x, W_pre1, W_pre2, W_upd1, W_upd2, gamma, beta,
                       kdr, damp, batch, Wb, starts_g, trig_rm, trigTb, xresTb);
    hipLaunchKernelGGL(kS_scatter, dim3(NB * 16), dim3(256), 0, stream,
                       starts_g, xresTb, trigTb, dp, W_up, SFTb);
    hipLaunchKernelGGL(kD_post, dim3(576), dim3(256), 0, stream,
                       x, starts_g, trig_rm, SFTb, Wb, out);
}